// Round 19
// baseline (116.629 us; speedup 1.0000x reference)
//
#include <hip/hip_runtime.h>
#include <hip/hip_bf16.h>

// FlashAttentionVarlen, bf16 32x32x16-MFMA flash attention, fp32 in/out.
// B=128 seqs (L in {128,256}), H=16, D=64, packed T=24576.
// R19 = R18 with the bug fixed: R18's FIRST-item tile-0 prefetch used a
// stale helper that dropped the h*D head offset (loaded head 0's K/V) ->
// absmax 1.71. Now ONE load_tile(t0, hoff, t) lambda serves the initial
// prefetch, in-item loads, and cross-item prefetch.
// Structure (R18): persistent 512 blocks x 4 striped items {bid+512k},
// cu[] staged to LDS once, no atomics, next item's tile-0 K/V loads issue
// before the current item's last-tile compute (cross-item prefetch).
// Numerics (R13..R17, absmax 0.0078): K bf16-hi LDS (33KB dbuf, folded XOR
// swizzle idx = BASE^(ks<<4)), Q hi+lo regs (QK = khi*qh + khi*ql),
// V bf16-hi, P bf16-hi, swapped QK (mfma32(A=K,B=Q)), in-register softmax,
// shfl_xor(32) P redistribute, one barrier per tile.

using bf16x8 = __attribute__((ext_vector_type(8))) short;
using u16x8  = __attribute__((ext_vector_type(8))) unsigned short;
using u32x4  = __attribute__((ext_vector_type(4))) unsigned;
using f32x16 = __attribute__((ext_vector_type(16))) float;

#define MFMA32(a, b, c) __builtin_amdgcn_mfma_f32_32x32x16_bf16((a), (b), (c), 0, 0, 0)

constexpr int H  = 16;
constexpr int D  = 64;
constexpr int RS = H * D;                              // packed row stride (floats)
constexpr int NBLK = 512;                              // persistent blocks
constexpr float QSCALE = 0.125f * 1.44269504088896f;   // 1/sqrt(64) * log2(e)
constexpr float THR    = 11.5f;                        // defer-max threshold (log2)

__device__ inline unsigned short bfbits(float x) {
  return __builtin_bit_cast(unsigned short, __float2bfloat16(x));
}
__device__ inline float bff(unsigned short u) {
  unsigned v = ((unsigned)u) << 16;
  return __builtin_bit_cast(float, v);
}
__device__ inline unsigned pack2(float x, float y) {
  return (unsigned)bfbits(x) | ((unsigned)bfbits(y) << 16);
}

__global__ __launch_bounds__(512, 2)
void fa_persist5_kernel(const float* __restrict__ qg, const float* __restrict__ kg,
                        const float* __restrict__ vg, const int* __restrict__ cu,
                        float* __restrict__ outg) {
  // double-buffered planes: K hi [key][d] (slot ^= key&7), V^T [d][key] (slot ^= d&7)
  __shared__ unsigned short kph[2][64 * 64];
  __shared__ unsigned short vth[2][64 * 64];
  __shared__ float lsc[8 * 32];          // per-wave lane->reg bounce (corr / 1/l)
  __shared__ int cu_s[129];              // whole cu table, staged once

  const int tid = (int)threadIdx.x, lane = tid & 63, w = tid >> 6;
  const int hi = lane >> 5, qj = lane & 31;
  const int qbase = w * 32;
  const bool hib = (hi != 0);
  const int bid = (int)blockIdx.x;

  if (tid < 129) cu_s[tid] = cu[tid];
  __syncthreads();

  // Folded swizzle bases: idx(row=kt*32+qj, slot=ks*2+hi) = BASE_kt ^ (ks<<4)
  const int m7   = qj & 7;
  const int boff = (hi ^ m7) << 3;
  const int KA0  = qj * 64 + boff;         // kt/n = 0 (shared by QK and PV)
  const int KA1  = (32 + qj) * 64 + boff;  // kt/n = 1

  // staging maps (512 threads: each stages 8 K-floats + 8 V-floats per tile)
  const int k_key = tid >> 3, kd0 = (tid & 7) * 8;
  const int kidx  = k_key * 64 + ((((kd0 >> 3)) ^ (k_key & 7)) << 3);
  const int v_d = tid & 63, vk0 = (tid >> 6) * 8;
  const int vidx  = v_d * 64 + ((((vk0 >> 3)) ^ (v_d & 7)) << 3);

  // ---- unified K/V tile load: seq base t0i, head offset hoffi, tile t ----
  float kf[8], vf[8];
  auto load_tile = [&](int t0i, int hoffi, int t) {
    const float* kr = kg + (size_t)(t0i + t * 64 + k_key) * RS + (size_t)(hoffi + kd0);
    const float4 f0 = *reinterpret_cast<const float4*>(kr);
    const float4 f1 = *reinterpret_cast<const float4*>(kr + 4);
    kf[0] = f0.x; kf[1] = f0.y; kf[2] = f0.z; kf[3] = f0.w;
    kf[4] = f1.x; kf[5] = f1.y; kf[6] = f1.z; kf[7] = f1.w;
    const float* vp = vg + (size_t)(t0i + t * 64 + vk0) * RS + (size_t)(hoffi + v_d);
#pragma unroll
    for (int i = 0; i < 8; ++i) vf[i] = vp[(size_t)i * RS];
  };
  auto cvt_write = [&](unsigned short* KP, unsigned short* VP) {
    u16x8 kh8, v8;
#pragma unroll
    for (int i = 0; i < 8; ++i) {
      kh8[i] = bfbits(kf[i]);
      v8[i]  = bfbits(vf[i]);
    }
    *reinterpret_cast<u16x8*>(KP + kidx) = kh8;
    *reinterpret_cast<u16x8*>(VP + vidx) = v8;
  };

  auto mix4 = [&](unsigned a0, unsigned a1, unsigned a2, unsigned a3) -> u32x4 {
    const unsigned t02 = hib ? a0 : a2;
    const unsigned t13 = hib ? a1 : a3;
    const unsigned c02 = (unsigned)__shfl_xor((int)t02, 32);
    const unsigned c13 = (unsigned)__shfl_xor((int)t13, 32);
    u32x4 r;
    r[0] = hib ? c02 : a0;
    r[1] = hib ? c13 : a1;
    r[2] = hib ? a2 : c02;
    r[3] = hib ? a3 : c13;
    return r;
  };
  auto build_pa = [&](const float* x) -> bf16x8 {
    return __builtin_bit_cast(bf16x8,
        mix4(pack2(x[0], x[1]), pack2(x[2], x[3]),
             pack2(x[4], x[5]), pack2(x[6], x[7])));
  };

#define LGKM_BARRIER()                                    \
  asm volatile("s_waitcnt lgkmcnt(0)" ::: "memory");      \
  __builtin_amdgcn_s_barrier();                           \
  asm volatile("" ::: "memory")

  // ---- first item's tile-0 prefetch (WITH head offset — R18's bug) ----
  load_tile(cu_s[bid >> 4], (bid & 15) * D, 0);

  for (int mI = 0; mI < 4; ++mI) {
    const int item = bid + mI * NBLK;          // deterministic stripe
    const int b = item >> 4, h = item & 15;
    const int t0 = cu_s[b];
    const int L  = cu_s[b + 1] - t0;
    const int nt = L >> 6;                     // 2 or 4
    const bool act = (qbase < L);              // wave-uniform
    const int hoff = h * D;
    // next item's tile-0 coords (for cross-item prefetch)
    const bool have_nxt = (mI < 3);
    const int nxt_t0   = have_nxt ? cu_s[(item + NBLK) >> 4] : 0;
    const int nxt_hoff = ((item + NBLK) & 15) * D;

    // ---- Q fragments (B operand), hi + lo planes (registers only) ----
    bf16x8 qh[4], ql[4];
    if (act) {
      const float* qrow = qg + (size_t)(t0 + qbase + qj) * RS + (size_t)hoff;
#pragma unroll
      for (int ks = 0; ks < 4; ++ks) {
        const int d0 = ks * 16 + hi * 8;
        const float4 f0 = *reinterpret_cast<const float4*>(qrow + d0);
        const float4 f1 = *reinterpret_cast<const float4*>(qrow + d0 + 4);
        const float f[8] = {f0.x, f0.y, f0.z, f0.w, f1.x, f1.y, f1.z, f1.w};
#pragma unroll
        for (int j = 0; j < 8; ++j) {
          const float x = f[j] * QSCALE;
          const unsigned short hs = bfbits(x);
          qh[ks][j] = (short)hs;
          ql[ks][j] = (short)bfbits(x - bff(hs));
        }
      }
    }

    f32x16 acc0, acc1;
#pragma unroll
    for (int r = 0; r < 16; ++r) { acc0[r] = 0.f; acc1[r] = 0.f; }
    float m = -1e30f, lsum = 0.f;

    // ---- compute one 64-key tile (verified R17 body) ----
    auto compute = [&](const unsigned short* KH, const unsigned short* VT) {
      f32x16 sc0, sc1;
#pragma unroll
      for (int r = 0; r < 16; ++r) { sc0[r] = 0.f; sc1[r] = 0.f; }
      __builtin_amdgcn_s_setprio(1);
#pragma unroll
      for (int ks = 0; ks < 4; ++ks) {
        const bf16x8 k0 = *reinterpret_cast<const bf16x8*>(&KH[KA0 ^ (ks << 4)]);
        sc0 = MFMA32(k0, qh[ks], sc0);
        sc0 = MFMA32(k0, ql[ks], sc0);
      }
#pragma unroll
      for (int ks = 0; ks < 4; ++ks) {
        const bf16x8 k1 = *reinterpret_cast<const bf16x8*>(&KH[KA1 ^ (ks << 4)]);
        sc1 = MFMA32(k1, qh[ks], sc1);
        sc1 = MFMA32(k1, ql[ks], sc1);
      }
      __builtin_amdgcn_s_setprio(0);

      float mx[8];
#pragma unroll
      for (int i = 0; i < 8; ++i) mx[i] = fmaxf(sc0[i], sc0[i + 8]);
#pragma unroll
      for (int i = 0; i < 8; ++i) mx[i] = fmaxf(mx[i], fmaxf(sc1[i], sc1[i + 8]));
#pragma unroll
      for (int i = 0; i < 4; ++i) mx[i] = fmaxf(mx[i], mx[i + 4]);
      float tmax = fmaxf(fmaxf(mx[0], mx[1]), fmaxf(mx[2], mx[3]));
      tmax = fmaxf(tmax, __shfl_xor(tmax, 32));
      if (!__all(tmax <= m + THR)) {
        const float newm = fmaxf(m, tmax);
        const float corr = exp2f(m - newm);
        m = newm;
        lsum *= corr;
        if (hi == 0) lsc[w * 32 + qj] = corr;
        __builtin_amdgcn_wave_barrier();
#pragma unroll
        for (int r = 0; r < 16; ++r) {
          const float c = lsc[w * 32 + ((r & 3) + 8 * (r >> 2) + 4 * hi)];
          acc0[r] *= c; acc1[r] *= c;
        }
      }
      float s0 = 0.f, s1 = 0.f, s2 = 0.f, s3 = 0.f;
#pragma unroll
      for (int r = 0; r < 16; r += 4) {
        sc0[r]     = exp2f(sc0[r]     - m); s0 += sc0[r];
        sc0[r + 1] = exp2f(sc0[r + 1] - m); s1 += sc0[r + 1];
        sc0[r + 2] = exp2f(sc0[r + 2] - m); s2 += sc0[r + 2];
        sc0[r + 3] = exp2f(sc0[r + 3] - m); s3 += sc0[r + 3];
      }
#pragma unroll
      for (int r = 0; r < 16; r += 4) {
        sc1[r]     = exp2f(sc1[r]     - m); s0 += sc1[r];
        sc1[r + 1] = exp2f(sc1[r + 1] - m); s1 += sc1[r + 1];
        sc1[r + 2] = exp2f(sc1[r + 2] - m); s2 += sc1[r + 2];
        sc1[r + 3] = exp2f(sc1[r + 3] - m); s3 += sc1[r + 3];
      }
      float ps = (s0 + s1) + (s2 + s3);
      lsum += ps + __shfl_xor(ps, 32);

#pragma unroll
      for (int ks2 = 0; ks2 < 4; ++ks2) {
        float px[8];
#pragma unroll
        for (int i = 0; i < 8; ++i)
          px[i] = (ks2 & 2) ? sc1[(ks2 & 1) * 8 + i] : sc0[(ks2 & 1) * 8 + i];
        const bf16x8 pah = build_pa(px);
        __builtin_amdgcn_s_setprio(1);
        const bf16x8 v0 = *reinterpret_cast<const bf16x8*>(&VT[KA0 ^ (ks2 << 4)]);
        const bf16x8 v1 = *reinterpret_cast<const bf16x8*>(&VT[KA1 ^ (ks2 << 4)]);
        acc0 = MFMA32(pah, v0, acc0);
        acc1 = MFMA32(pah, v1, acc1);
        __builtin_amdgcn_s_setprio(0);
      }
    };

    // ---- unrolled tile schedule with cross-item prefetch ----
    // invariant at item top: kf/vf hold THIS item's tile 0
    cvt_write(kph[0], vth[0]);
    load_tile(t0, hoff, 1);
    LGKM_BARRIER();

    if (act) compute(kph[0], vth[0]);     // tile 0
    cvt_write(kph[1], vth[1]);
    if (nt > 2) load_tile(t0, hoff, 2);
    else if (have_nxt) load_tile(nxt_t0, nxt_hoff, 0);   // cross-item prefetch
    LGKM_BARRIER();

    if (act) compute(kph[1], vth[1]);     // tile 1
    if (nt > 2) {
      cvt_write(kph[0], vth[0]);
      load_tile(t0, hoff, 3);
      LGKM_BARRIER();
      if (act) compute(kph[0], vth[0]);   // tile 2
      cvt_write(kph[1], vth[1]);
      if (have_nxt) load_tile(nxt_t0, nxt_hoff, 0);      // cross-item prefetch
      LGKM_BARRIER();
      if (act) compute(kph[1], vth[1]);   // tile 3
    }

    // ---- epilogue ----
    if (act) {
      if (hi == 0) lsc[w * 32 + qj] = 1.0f / lsum;
      __builtin_amdgcn_wave_barrier();
#pragma unroll
      for (int r = 0; r < 16; ++r) {
        const int row = (r & 3) + 8 * (r >> 2) + 4 * hi;
        const float li = lsc[w * 32 + row];
        float* op = outg + (size_t)(t0 + qbase + row) * RS + (size_t)hoff + qj;
        op[0]  = acc0[r] * li;
        op[32] = acc1[r] * li;
      }
    }
    // buffer-reuse ordering across items: next item's first LGKM_BARRIER
    // follows every wave's last read of both buffers.
  }
#undef LGKM_BARRIER
}

extern "C" void kernel_launch(void* const* d_in, const int* in_sizes, int n_in,
                              void* d_out, int out_size, void* d_ws, size_t ws_size,
                              hipStream_t stream) {
  (void)in_sizes; (void)n_in; (void)d_ws; (void)ws_size; (void)out_size;
  const float* q  = (const float*)d_in[0];
  const float* k  = (const float*)d_in[1];
  const float* v  = (const float*)d_in[2];
  const int*   cu = (const int*)d_in[3];
  float* out = (float*)d_out;

  // persistent deterministic: 512 blocks x 4 striped items, no atomics
  fa_persist5_kernel<<<dim3(NBLK), dim3(512), 0, stream>>>(q, k, v, cu, out);
}